// Round 1
// baseline (1706.795 us; speedup 1.0000x reference)
//
#include <hip/hip_runtime.h>
#include <math.h>

// ---------------------------------------------------------------------------
// RecurrentNatureCNN: conv1(8x8,s4) -> conv2(4x4,s2) -> conv3(3x3,s1) -> FC
//                     -> LSTM(T=64,B=32,H=256)
// All fp32 this round (correctness anchor). N = T*B = 2048 images.
// ---------------------------------------------------------------------------

#define NIMG 2048

// ---- generic small transpose: in (R,C) -> out (C,R) -----------------------
__global__ void transpose_kernel(const float* __restrict__ in, float* __restrict__ out,
                                 int R, int C) {
    int idx = blockIdx.x * 256 + threadIdx.x;
    if (idx < R * C) {
        int r = idx / C, c = idx - r * C;
        out[c * R + r] = in[idx];
    }
}

// ---- conv1: x (n,4,64,64)/255 -> relu -> (n,32,15,15) ----------------------
// block = 1 image, 256 threads. x image staged in LDS (64 KB). thread = output
// position (oy,ox) (225 active), acc[32] over out-channels, weights via
// uniform loads (broadcast / s_load).
__global__ __launch_bounds__(256) void conv1_kernel(const float* __restrict__ x,
                                                    const float* __restrict__ w,
                                                    const float* __restrict__ b,
                                                    float* __restrict__ out) {
    __shared__ float xs[4 * 64 * 64];  // 65536 B
    int n = blockIdx.x;
    int tid = threadIdx.x;
    const float* xp = x + (size_t)n * 16384;
    const float inv = 1.0f / 255.0f;
    for (int i = tid * 4; i < 16384; i += 1024) {
        float4 v = *(const float4*)(xp + i);
        xs[i + 0] = v.x * inv;
        xs[i + 1] = v.y * inv;
        xs[i + 2] = v.z * inv;
        xs[i + 3] = v.w * inv;
    }
    __syncthreads();
    if (tid < 225) {
        int oy = tid / 15, ox = tid - oy * 15;
        float acc[32];
#pragma unroll
        for (int oc = 0; oc < 32; ++oc) acc[oc] = b[oc];
        for (int ic = 0; ic < 4; ++ic) {
#pragma unroll
            for (int ky = 0; ky < 8; ++ky) {
                const float* xrow = &xs[(ic * 64 + oy * 4 + ky) * 64 + ox * 4];
                float xr[8];
#pragma unroll
                for (int kx = 0; kx < 8; ++kx) xr[kx] = xrow[kx];
                const float* wrow = w + ic * 64 + ky * 8;  // + oc*256
#pragma unroll
                for (int oc = 0; oc < 32; ++oc) {
                    const float* wr = wrow + oc * 256;
#pragma unroll
                    for (int kx = 0; kx < 8; ++kx) acc[oc] += xr[kx] * wr[kx];
                }
            }
        }
        float* op = out + (size_t)n * 32 * 225 + tid;
#pragma unroll
        for (int oc = 0; oc < 32; ++oc) op[oc * 225] = fmaxf(acc[oc], 0.0f);
    }
}

// ---- conv2: z1 (n,32,15,15) -> relu -> (n,64,6,6) --------------------------
// block = 2 images, 256 threads. Image staged in LDS with rows padded to 16.
// lane = out-channel (64 = wave), wave handles 3 output rows of one image.
// weights pre-transposed to w2t[(ic*4+ky)*4+kx][oc].
__global__ __launch_bounds__(256) void conv2_kernel(const float* __restrict__ x,
                                                    const float* __restrict__ wt,
                                                    const float* __restrict__ bias,
                                                    float* __restrict__ out) {
    __shared__ float xs[2][32 * 15 * 16];  // 61440 B
    int tid = threadIdx.x;
    int n0 = blockIdx.x * 2;
    for (int img = 0; img < 2; ++img) {
        const float* src = x + (size_t)(n0 + img) * 7200;
        for (int s = tid; s < 7200; s += 256) {
            int ic = s / 225;
            int rem = s - ic * 225;
            int r = rem / 15;
            int c = rem - r * 15;
            xs[img][(ic * 15 + r) * 16 + c] = src[s];
        }
    }
    __syncthreads();
    int lane = tid & 63, wave = tid >> 6;
    int img = wave >> 1;
    int rowHalf = wave & 1;
    int n = n0 + img;
    float bv = bias[lane];
    float* op = out + (size_t)n * 2304 + lane * 36;
    for (int q = 0; q < 3; ++q) {
        int oy = rowHalf * 3 + q;
        float acc[6];
#pragma unroll
        for (int u = 0; u < 6; ++u) acc[u] = bv;
        for (int ic = 0; ic < 32; ++ic) {
#pragma unroll
            for (int ky = 0; ky < 4; ++ky) {
                const float* xrow = &xs[img][(ic * 15 + oy * 2 + ky) * 16];
                float xr[16];
                *(float4*)&xr[0]  = *(const float4*)&xrow[0];
                *(float4*)&xr[4]  = *(const float4*)&xrow[4];
                *(float4*)&xr[8]  = *(const float4*)&xrow[8];
                *(float4*)&xr[12] = *(const float4*)&xrow[12];
                const float* wp = wt + ((ic * 4 + ky) * 4) * 64 + lane;
#pragma unroll
                for (int kx = 0; kx < 4; ++kx) {
                    float wv = wp[kx * 64];
#pragma unroll
                    for (int u = 0; u < 6; ++u) acc[u] += xr[u * 2 + kx] * wv;
                }
            }
        }
#pragma unroll
        for (int u = 0; u < 6; ++u) op[oy * 6 + u] = fmaxf(acc[u], 0.0f);
    }
}

// ---- conv3: z2 (n,64,6,6) -> relu -> (n,64,4,4) ----------------------------
// block = 4 images, 256 threads, wave = image, lane = out-channel.
// weights pre-transposed to w3t[(ic*3+ky)*3+kx][oc]. LDS rows padded to 8.
__global__ __launch_bounds__(256) void conv3_kernel(const float* __restrict__ x,
                                                    const float* __restrict__ wt,
                                                    const float* __restrict__ bias,
                                                    float* __restrict__ out) {
    __shared__ float xs[4][64 * 6 * 8];  // 49152 B
    int tid = threadIdx.x;
    int n0 = blockIdx.x * 4;
    for (int img = 0; img < 4; ++img) {
        const float* src = x + (size_t)(n0 + img) * 2304;
        for (int s = tid; s < 2304; s += 256) {
            int ic = s / 36;
            int rem = s - ic * 36;
            int r = rem / 6;
            int c = rem - r * 6;
            xs[img][(ic * 6 + r) * 8 + c] = src[s];
        }
    }
    __syncthreads();
    int lane = tid & 63, wave = tid >> 6;
    int n = n0 + wave;
    float bv = bias[lane];
    float* op = out + (size_t)n * 1024 + lane * 16;
    for (int oy = 0; oy < 4; ++oy) {
        float acc[4];
#pragma unroll
        for (int u = 0; u < 4; ++u) acc[u] = bv;
        for (int ic = 0; ic < 64; ++ic) {
#pragma unroll
            for (int ky = 0; ky < 3; ++ky) {
                const float* xrow = &xs[wave][(ic * 6 + oy + ky) * 8];
                float xr[8];
                *(float4*)&xr[0] = *(const float4*)&xrow[0];
                *(float4*)&xr[4] = *(const float4*)&xrow[4];
                const float* wp = wt + ((ic * 3 + ky) * 3) * 64 + lane;
#pragma unroll
                for (int kx = 0; kx < 3; ++kx) {
                    float wv = wp[kx * 64];
#pragma unroll
                    for (int u = 0; u < 4; ++u) acc[u] += xr[u + kx] * wv;
                }
            }
        }
#pragma unroll
        for (int u = 0; u < 4; ++u) op[oy * 4 + u] = fmaxf(acc[u], 0.0f);
    }
}

// ---- GEMM: C(M,N) = [relu]( A(M,K) @ B(N,K)^T + bias [+ bias2] ) -----------
// 64x64 tile, BK=16, 256 threads, 4x4 micro-tile.
__global__ __launch_bounds__(256) void gemm_bt(const float* __restrict__ A,
                                               const float* __restrict__ B,
                                               const float* __restrict__ bias,
                                               const float* __restrict__ bias2,
                                               float* __restrict__ C,
                                               int M, int N, int K, int relu) {
    __shared__ float As[16][68];
    __shared__ float Bs[16][68];
    int tid = threadIdx.x;
    int m0 = blockIdx.y * 64, n0 = blockIdx.x * 64;
    int tx = tid & 15, ty = tid >> 4;
    int lr = tid >> 2;
    int lk = (tid & 3) * 4;
    const float* Ap = A + (size_t)(m0 + lr) * K + lk;
    const float* Bp = B + (size_t)(n0 + lr) * K + lk;
    float acc[4][4];
#pragma unroll
    for (int i = 0; i < 4; ++i)
#pragma unroll
        for (int j = 0; j < 4; ++j) acc[i][j] = 0.0f;

    for (int k0 = 0; k0 < K; k0 += 16) {
        float4 av = *(const float4*)(Ap + k0);
        float4 bv = *(const float4*)(Bp + k0);
        __syncthreads();
        As[lk + 0][lr] = av.x;
        As[lk + 1][lr] = av.y;
        As[lk + 2][lr] = av.z;
        As[lk + 3][lr] = av.w;
        Bs[lk + 0][lr] = bv.x;
        Bs[lk + 1][lr] = bv.y;
        Bs[lk + 2][lr] = bv.z;
        Bs[lk + 3][lr] = bv.w;
        __syncthreads();
#pragma unroll
        for (int kk = 0; kk < 16; ++kk) {
            float a[4], b[4];
            *(float4*)a = *(const float4*)&As[kk][ty * 4];
            *(float4*)b = *(const float4*)&Bs[kk][tx * 4];
#pragma unroll
            for (int i = 0; i < 4; ++i)
#pragma unroll
                for (int j = 0; j < 4; ++j) acc[i][j] += a[i] * b[j];
        }
    }
    float bb[4];
#pragma unroll
    for (int j = 0; j < 4; ++j) {
        float v = bias[n0 + tx * 4 + j];
        if (bias2) v += bias2[n0 + tx * 4 + j];
        bb[j] = v;
    }
#pragma unroll
    for (int i = 0; i < 4; ++i) {
        float4 o;
        o.x = acc[i][0] + bb[0];
        o.y = acc[i][1] + bb[1];
        o.z = acc[i][2] + bb[2];
        o.w = acc[i][3] + bb[3];
        if (relu) {
            o.x = fmaxf(o.x, 0.0f);
            o.y = fmaxf(o.y, 0.0f);
            o.z = fmaxf(o.z, 0.0f);
            o.w = fmaxf(o.w, 0.0f);
        }
        *(float4*)&C[(size_t)(m0 + ty * 4 + i) * N + n0 + tx * 4] = o;
    }
}

// ---- LSTM: 32 blocks (one per env), 256 threads ----------------------------
// gi (2048,1024) holds feats@w_ih^T + b_ih + b_hh (precomputed).
// whht (256,1024) = w_hh^T so the per-step stream is coalesced dwordx4.
// thread j computes gate columns 4j..4j+3; after barrier thread j owns
// hidden unit j (c in register, h in LDS). Mask via linearity: (h*m)@W = m*(h@W).
__global__ __launch_bounds__(256) void lstm_kernel(const float* __restrict__ gi,
                                                   const float* __restrict__ whht,
                                                   const int* __restrict__ done,
                                                   const float* __restrict__ h0,
                                                   const float* __restrict__ c0,
                                                   float* __restrict__ out) {
    __shared__ float h[256];
    __shared__ float gates[1024];
    int b = blockIdx.x, tid = threadIdx.x;
    float c = c0[b * 256 + tid];
    h[tid] = h0[b * 256 + tid];
    int col0 = tid * 4;
    __syncthreads();
    for (int t = 0; t < 64; ++t) {
        int row = t * 32 + b;
        float m = 1.0f - (float)done[row];
        float s0 = 0.0f, s1 = 0.0f, s2 = 0.0f, s3 = 0.0f;
        for (int k = 0; k < 256; k += 4) {
            float4 hk = *(const float4*)&h[k];
            const float* wp = whht + (size_t)k * 1024 + col0;
            float4 w0 = *(const float4*)(wp);
            float4 w1 = *(const float4*)(wp + 1024);
            float4 w2 = *(const float4*)(wp + 2048);
            float4 w3 = *(const float4*)(wp + 3072);
            s0 += hk.x * w0.x + hk.y * w1.x + hk.z * w2.x + hk.w * w3.x;
            s1 += hk.x * w0.y + hk.y * w1.y + hk.z * w2.y + hk.w * w3.y;
            s2 += hk.x * w0.z + hk.y * w1.z + hk.z * w2.z + hk.w * w3.z;
            s3 += hk.x * w0.w + hk.y * w1.w + hk.z * w2.w + hk.w * w3.w;
        }
        float4 g4 = *(const float4*)(gi + (size_t)row * 1024 + col0);
        float4 gv;
        gv.x = g4.x + m * s0;
        gv.y = g4.y + m * s1;
        gv.z = g4.z + m * s2;
        gv.w = g4.w + m * s3;
        *(float4*)&gates[col0] = gv;
        __syncthreads();
        float g_i = gates[tid];
        float g_f = gates[256 + tid];
        float g_g = gates[512 + tid];
        float g_o = gates[768 + tid];
        float cm = c * m;
        float si = 1.0f / (1.0f + __expf(-g_i));
        float sf = 1.0f / (1.0f + __expf(-g_f));
        float so = 1.0f / (1.0f + __expf(-g_o));
        float tg = tanhf(g_g);
        c = sf * cm + si * tg;
        float hn = so * tanhf(c);
        h[tid] = hn;
        out[(size_t)row * 256 + tid] = hn;
        __syncthreads();
    }
}

// ---------------------------------------------------------------------------
extern "C" void kernel_launch(void* const* d_in, const int* in_sizes, int n_in,
                              void* d_out, int out_size, void* d_ws, size_t ws_size,
                              hipStream_t stream) {
    const float* x   = (const float*)d_in[0];
    const int*   done = (const int*)d_in[1];
    const float* w1  = (const float*)d_in[2];
    const float* b1  = (const float*)d_in[3];
    const float* w2  = (const float*)d_in[4];
    const float* b2  = (const float*)d_in[5];
    const float* w3  = (const float*)d_in[6];
    const float* b3  = (const float*)d_in[7];
    const float* fcw = (const float*)d_in[8];
    const float* fcb = (const float*)d_in[9];
    const float* wih = (const float*)d_in[10];
    const float* whh = (const float*)d_in[11];
    const float* bih = (const float*)d_in[12];
    const float* bhh = (const float*)d_in[13];
    const float* h0  = (const float*)d_in[14];
    const float* c0  = (const float*)d_in[15];
    float* out = (float*)d_out;
    float* ws = (float*)d_ws;

    // workspace layout (floats); z3/feats/gi reuse z1's region (z1 dead then)
    float* z1    = ws + 0;          // 14745600
    float* z2    = ws + 14745600;   //  4718592 (ends 19464192)
    float* z3    = ws + 0;          //  2097152
    float* feats = ws + 2097152;    //  1048576
    float* gi    = ws + 3145728;    //  2097152 (ends 5242880)
    float* w2t   = ws + 19464192;   //    32768
    float* w3t   = ws + 19496960;   //    36864
    float* whht  = ws + 19533824;   //   262144 (ends 19795968 -> 79.2 MB)

    transpose_kernel<<<(64 * 512 + 255) / 256, 256, 0, stream>>>(w2, w2t, 64, 512);
    transpose_kernel<<<(64 * 576 + 255) / 256, 256, 0, stream>>>(w3, w3t, 64, 576);
    transpose_kernel<<<(1024 * 256 + 255) / 256, 256, 0, stream>>>(whh, whht, 1024, 256);

    conv1_kernel<<<NIMG, 256, 0, stream>>>(x, w1, b1, z1);
    conv2_kernel<<<NIMG / 2, 256, 0, stream>>>(z1, w2t, b2, z2);
    conv3_kernel<<<NIMG / 4, 256, 0, stream>>>(z2, w3t, b3, z3);

    gemm_bt<<<dim3(512 / 64, NIMG / 64), 256, 0, stream>>>(z3, fcw, fcb, nullptr, feats,
                                                           NIMG, 512, 1024, 1);
    gemm_bt<<<dim3(1024 / 64, NIMG / 64), 256, 0, stream>>>(feats, wih, bih, bhh, gi,
                                                            NIMG, 1024, 512, 0);

    lstm_kernel<<<32, 256, 0, stream>>>(gi, whht, done, h0, c0, out);
}

// Round 2
// 1284.681 us; speedup vs baseline: 1.3286x; 1.3286x over previous
//
#include <hip/hip_runtime.h>
#include <math.h>

// ---------------------------------------------------------------------------
// RecurrentNatureCNN: conv1(8x8,s4) -> conv2(4x4,s2) -> conv3(3x3,s1) -> FC
//                     -> LSTM(T=64,B=32,H=256)
// fp32. N = T*B = 2048 images.
// R1: conv1 -> 1024 thr / 4 oc-groups (occupancy 24%->~90%);
//     LSTM  -> 1024 thr, 1 gate-col/thread.
// ---------------------------------------------------------------------------

#define NIMG 2048

// ---- generic small transpose: in (R,C) -> out (C,R) -----------------------
__global__ void transpose_kernel(const float* __restrict__ in, float* __restrict__ out,
                                 int R, int C) {
    int idx = blockIdx.x * 256 + threadIdx.x;
    if (idx < R * C) {
        int r = idx / C, c = idx - r * C;
        out[c * R + r] = in[idx];
    }
}

// ---- conv1: x (n,4,64,64)/255 -> relu -> (n,32,15,15) ----------------------
// block = 1 image, 1024 threads (16 waves). wave w: oc-group g=w&3 (8 oc),
// position segment (w>>2)*64+lane. Image staged in LDS (64 KB -> 2 blocks/CU
// = 32 waves/CU). Weight addresses wave-uniform (readfirstlane) -> s_load.
__global__ __launch_bounds__(1024) void conv1_kernel(const float* __restrict__ x,
                                                     const float* __restrict__ w,
                                                     const float* __restrict__ b,
                                                     float* __restrict__ out) {
    __shared__ float xs[4 * 64 * 64];  // 65536 B
    int n = blockIdx.x;
    int tid = threadIdx.x;
    const float* xp = x + (size_t)n * 16384;
    const float inv = 1.0f / 255.0f;
    for (int i = tid * 4; i < 16384; i += 4096) {
        float4 v = *(const float4*)(xp + i);
        xs[i + 0] = v.x * inv;
        xs[i + 1] = v.y * inv;
        xs[i + 2] = v.z * inv;
        xs[i + 3] = v.w * inv;
    }
    __syncthreads();
    int lane = tid & 63, wave = tid >> 6;
    int gg = __builtin_amdgcn_readfirstlane(wave & 3);  // oc group, wave-uniform
    int pos = (wave >> 2) * 64 + lane;                  // 0..255
    if (pos < 225) {
        int oy = pos / 15, ox = pos - oy * 15;
        float acc[8];
        const float* bp = b + gg * 8;
#pragma unroll
        for (int u = 0; u < 8; ++u) acc[u] = bp[u];
        for (int ic = 0; ic < 4; ++ic) {
#pragma unroll
            for (int ky = 0; ky < 8; ++ky) {
                const float* xrow = &xs[(ic * 64 + oy * 4 + ky) * 64 + ox * 4];
                float xr[8];
                *(float4*)&xr[0] = *(const float4*)&xrow[0];
                *(float4*)&xr[4] = *(const float4*)&xrow[4];
                const float* wrow = w + (gg * 8) * 256 + ic * 64 + ky * 8;
#pragma unroll
                for (int u = 0; u < 8; ++u) {
                    const float* wr = wrow + u * 256;
#pragma unroll
                    for (int kx = 0; kx < 8; ++kx) acc[u] += xr[kx] * wr[kx];
                }
            }
        }
        float* op = out + (size_t)n * 7200 + (gg * 8) * 225 + pos;
#pragma unroll
        for (int u = 0; u < 8; ++u) op[u * 225] = fmaxf(acc[u], 0.0f);
    }
}

// ---- conv2: z1 (n,32,15,15) -> relu -> (n,64,6,6) --------------------------
// block = 2 images, 256 threads. Image staged in LDS with rows padded to 16.
// lane = out-channel (64 = wave), wave handles 3 output rows of one image.
// weights pre-transposed to w2t[(ic*4+ky)*4+kx][oc].
__global__ __launch_bounds__(256) void conv2_kernel(const float* __restrict__ x,
                                                    const float* __restrict__ wt,
                                                    const float* __restrict__ bias,
                                                    float* __restrict__ out) {
    __shared__ float xs[2][32 * 15 * 16];  // 61440 B
    int tid = threadIdx.x;
    int n0 = blockIdx.x * 2;
    for (int img = 0; img < 2; ++img) {
        const float* src = x + (size_t)(n0 + img) * 7200;
        for (int s = tid; s < 7200; s += 256) {
            int ic = s / 225;
            int rem = s - ic * 225;
            int r = rem / 15;
            int c = rem - r * 15;
            xs[img][(ic * 15 + r) * 16 + c] = src[s];
        }
    }
    __syncthreads();
    int lane = tid & 63, wave = tid >> 6;
    int img = wave >> 1;
    int rowHalf = wave & 1;
    int n = n0 + img;
    float bv = bias[lane];
    float* op = out + (size_t)n * 2304 + lane * 36;
    for (int q = 0; q < 3; ++q) {
        int oy = rowHalf * 3 + q;
        float acc[6];
#pragma unroll
        for (int u = 0; u < 6; ++u) acc[u] = bv;
        for (int ic = 0; ic < 32; ++ic) {
#pragma unroll
            for (int ky = 0; ky < 4; ++ky) {
                const float* xrow = &xs[img][(ic * 15 + oy * 2 + ky) * 16];
                float xr[16];
                *(float4*)&xr[0]  = *(const float4*)&xrow[0];
                *(float4*)&xr[4]  = *(const float4*)&xrow[4];
                *(float4*)&xr[8]  = *(const float4*)&xrow[8];
                *(float4*)&xr[12] = *(const float4*)&xrow[12];
                const float* wp = wt + ((ic * 4 + ky) * 4) * 64 + lane;
#pragma unroll
                for (int kx = 0; kx < 4; ++kx) {
                    float wv = wp[kx * 64];
#pragma unroll
                    for (int u = 0; u < 6; ++u) acc[u] += xr[u * 2 + kx] * wv;
                }
            }
        }
#pragma unroll
        for (int u = 0; u < 6; ++u) op[oy * 6 + u] = fmaxf(acc[u], 0.0f);
    }
}

// ---- conv3: z2 (n,64,6,6) -> relu -> (n,64,4,4) ----------------------------
// block = 4 images, 256 threads, wave = image, lane = out-channel.
// weights pre-transposed to w3t[(ic*3+ky)*3+kx][oc]. LDS rows padded to 8.
__global__ __launch_bounds__(256) void conv3_kernel(const float* __restrict__ x,
                                                    const float* __restrict__ wt,
                                                    const float* __restrict__ bias,
                                                    float* __restrict__ out) {
    __shared__ float xs[4][64 * 6 * 8];  // 49152 B
    int tid = threadIdx.x;
    int n0 = blockIdx.x * 4;
    for (int img = 0; img < 4; ++img) {
        const float* src = x + (size_t)(n0 + img) * 2304;
        for (int s = tid; s < 2304; s += 256) {
            int ic = s / 36;
            int rem = s - ic * 36;
            int r = rem / 6;
            int c = rem - r * 6;
            xs[img][(ic * 6 + r) * 8 + c] = src[s];
        }
    }
    __syncthreads();
    int lane = tid & 63, wave = tid >> 6;
    int n = n0 + wave;
    float bv = bias[lane];
    float* op = out + (size_t)n * 1024 + lane * 16;
    for (int oy = 0; oy < 4; ++oy) {
        float acc[4];
#pragma unroll
        for (int u = 0; u < 4; ++u) acc[u] = bv;
        for (int ic = 0; ic < 64; ++ic) {
#pragma unroll
            for (int ky = 0; ky < 3; ++ky) {
                const float* xrow = &xs[wave][(ic * 6 + oy + ky) * 8];
                float xr[8];
                *(float4*)&xr[0] = *(const float4*)&xrow[0];
                *(float4*)&xr[4] = *(const float4*)&xrow[4];
                const float* wp = wt + ((ic * 3 + ky) * 3) * 64 + lane;
#pragma unroll
                for (int kx = 0; kx < 3; ++kx) {
                    float wv = wp[kx * 64];
#pragma unroll
                    for (int u = 0; u < 4; ++u) acc[u] += xr[u + kx] * wv;
                }
            }
        }
#pragma unroll
        for (int u = 0; u < 4; ++u) op[oy * 4 + u] = fmaxf(acc[u], 0.0f);
    }
}

// ---- GEMM: C(M,N) = [relu]( A(M,K) @ B(N,K)^T + bias [+ bias2] ) -----------
// 64x64 tile, BK=16, 256 threads, 4x4 micro-tile.
__global__ __launch_bounds__(256) void gemm_bt(const float* __restrict__ A,
                                               const float* __restrict__ B,
                                               const float* __restrict__ bias,
                                               const float* __restrict__ bias2,
                                               float* __restrict__ C,
                                               int M, int N, int K, int relu) {
    __shared__ float As[16][68];
    __shared__ float Bs[16][68];
    int tid = threadIdx.x;
    int m0 = blockIdx.y * 64, n0 = blockIdx.x * 64;
    int tx = tid & 15, ty = tid >> 4;
    int lr = tid >> 2;
    int lk = (tid & 3) * 4;
    const float* Ap = A + (size_t)(m0 + lr) * K + lk;
    const float* Bp = B + (size_t)(n0 + lr) * K + lk;
    float acc[4][4];
#pragma unroll
    for (int i = 0; i < 4; ++i)
#pragma unroll
        for (int j = 0; j < 4; ++j) acc[i][j] = 0.0f;

    for (int k0 = 0; k0 < K; k0 += 16) {
        float4 av = *(const float4*)(Ap + k0);
        float4 bv = *(const float4*)(Bp + k0);
        __syncthreads();
        As[lk + 0][lr] = av.x;
        As[lk + 1][lr] = av.y;
        As[lk + 2][lr] = av.z;
        As[lk + 3][lr] = av.w;
        Bs[lk + 0][lr] = bv.x;
        Bs[lk + 1][lr] = bv.y;
        Bs[lk + 2][lr] = bv.z;
        Bs[lk + 3][lr] = bv.w;
        __syncthreads();
#pragma unroll
        for (int kk = 0; kk < 16; ++kk) {
            float a[4], b[4];
            *(float4*)a = *(const float4*)&As[kk][ty * 4];
            *(float4*)b = *(const float4*)&Bs[kk][tx * 4];
#pragma unroll
            for (int i = 0; i < 4; ++i)
#pragma unroll
                for (int j = 0; j < 4; ++j) acc[i][j] += a[i] * b[j];
        }
    }
    float bb[4];
#pragma unroll
    for (int j = 0; j < 4; ++j) {
        float v = bias[n0 + tx * 4 + j];
        if (bias2) v += bias2[n0 + tx * 4 + j];
        bb[j] = v;
    }
#pragma unroll
    for (int i = 0; i < 4; ++i) {
        float4 o;
        o.x = acc[i][0] + bb[0];
        o.y = acc[i][1] + bb[1];
        o.z = acc[i][2] + bb[2];
        o.w = acc[i][3] + bb[3];
        if (relu) {
            o.x = fmaxf(o.x, 0.0f);
            o.y = fmaxf(o.y, 0.0f);
            o.z = fmaxf(o.z, 0.0f);
            o.w = fmaxf(o.w, 0.0f);
        }
        *(float4*)&C[(size_t)(m0 + ty * 4 + i) * N + n0 + tx * 4] = o;
    }
}

// ---- LSTM: 32 blocks (one per env), 1024 threads ---------------------------
// gi (2048,1024) holds feats@w_ih^T + b_ih + b_hh (precomputed).
// whht (256,1024) = w_hh^T. Thread j computes gate column j (256 FMA/step),
// h broadcast from LDS, weights streamed coalesced from L2 (whht stays
// L2-resident, 1 MB). Threads <256 own hidden unit (c in reg, h in LDS).
// Mask via linearity: (h*m)@W = m*(h@W).
__global__ __launch_bounds__(1024) void lstm_kernel(const float* __restrict__ gi,
                                                    const float* __restrict__ whht,
                                                    const int* __restrict__ done,
                                                    const float* __restrict__ h0,
                                                    const float* __restrict__ c0,
                                                    float* __restrict__ out) {
    __shared__ float h[256];
    __shared__ float gates[1024];
    int b = blockIdx.x, tid = threadIdx.x;
    float c = 0.0f;
    if (tid < 256) {
        c = c0[b * 256 + tid];
        h[tid] = h0[b * 256 + tid];
    }
    __syncthreads();
    const float* wcol = whht + tid;  // w[k][tid], row stride 1024
    for (int t = 0; t < 64; ++t) {
        int row = t * 32 + b;
        float m = 1.0f - (float)done[row];
        float s = 0.0f;
#pragma unroll 8
        for (int k = 0; k < 256; k += 4) {
            float4 hk = *(const float4*)&h[k];
            float w0 = wcol[(size_t)(k + 0) * 1024];
            float w1 = wcol[(size_t)(k + 1) * 1024];
            float w2 = wcol[(size_t)(k + 2) * 1024];
            float w3 = wcol[(size_t)(k + 3) * 1024];
            s += hk.x * w0 + hk.y * w1 + hk.z * w2 + hk.w * w3;
        }
        float gv = gi[(size_t)row * 1024 + tid] + m * s;
        gates[tid] = gv;
        __syncthreads();
        if (tid < 256) {
            float g_i = gates[tid];
            float g_f = gates[256 + tid];
            float g_g = gates[512 + tid];
            float g_o = gates[768 + tid];
            float si = 1.0f / (1.0f + __expf(-g_i));
            float sf = 1.0f / (1.0f + __expf(-g_f));
            float so = 1.0f / (1.0f + __expf(-g_o));
            float tg = tanhf(g_g);
            c = sf * (c * m) + si * tg;
            float hn = so * tanhf(c);
            h[tid] = hn;
            out[(size_t)row * 256 + tid] = hn;
        }
        __syncthreads();
    }
}

// ---------------------------------------------------------------------------
extern "C" void kernel_launch(void* const* d_in, const int* in_sizes, int n_in,
                              void* d_out, int out_size, void* d_ws, size_t ws_size,
                              hipStream_t stream) {
    const float* x   = (const float*)d_in[0];
    const int*   done = (const int*)d_in[1];
    const float* w1  = (const float*)d_in[2];
    const float* b1  = (const float*)d_in[3];
    const float* w2  = (const float*)d_in[4];
    const float* b2  = (const float*)d_in[5];
    const float* w3  = (const float*)d_in[6];
    const float* b3  = (const float*)d_in[7];
    const float* fcw = (const float*)d_in[8];
    const float* fcb = (const float*)d_in[9];
    const float* wih = (const float*)d_in[10];
    const float* whh = (const float*)d_in[11];
    const float* bih = (const float*)d_in[12];
    const float* bhh = (const float*)d_in[13];
    const float* h0  = (const float*)d_in[14];
    const float* c0  = (const float*)d_in[15];
    float* out = (float*)d_out;
    float* ws = (float*)d_ws;

    // workspace layout (floats); z3/feats/gi reuse z1's region (z1 dead then)
    float* z1    = ws + 0;          // 14745600
    float* z2    = ws + 14745600;   //  4718592 (ends 19464192)
    float* z3    = ws + 0;          //  2097152
    float* feats = ws + 2097152;    //  1048576
    float* gi    = ws + 3145728;    //  2097152 (ends 5242880)
    float* w2t   = ws + 19464192;   //    32768
    float* w3t   = ws + 19496960;   //    36864
    float* whht  = ws + 19533824;   //   262144 (ends 19795968 -> 79.2 MB)

    transpose_kernel<<<(64 * 512 + 255) / 256, 256, 0, stream>>>(w2, w2t, 64, 512);
    transpose_kernel<<<(64 * 576 + 255) / 256, 256, 0, stream>>>(w3, w3t, 64, 576);
    transpose_kernel<<<(1024 * 256 + 255) / 256, 256, 0, stream>>>(whh, whht, 1024, 256);

    conv1_kernel<<<NIMG, 1024, 0, stream>>>(x, w1, b1, z1);
    conv2_kernel<<<NIMG / 2, 256, 0, stream>>>(z1, w2t, b2, z2);
    conv3_kernel<<<NIMG / 4, 256, 0, stream>>>(z2, w3t, b3, z3);

    gemm_bt<<<dim3(512 / 64, NIMG / 64), 256, 0, stream>>>(z3, fcw, fcb, nullptr, feats,
                                                           NIMG, 512, 1024, 1);
    gemm_bt<<<dim3(1024 / 64, NIMG / 64), 256, 0, stream>>>(feats, wih, bih, bhh, gi,
                                                            NIMG, 1024, 512, 0);

    lstm_kernel<<<32, 1024, 0, stream>>>(gi, whht, done, h0, c0, out);
}